// Round 1
// baseline (644.849 us; speedup 1.0000x reference)
//
#include <hip/hip_runtime.h>
#include <hip/hip_bf16.h>

// Problem constants
#define Tt 4096   // B*L tokens
#define Dd 1024   // model dim
#define Ee 8      // experts
#define Kk 2      // top-k
#define Ff 4096   // DFF

using f32x4  = __attribute__((ext_vector_type(4))) float;
using bf16x8 = __attribute__((ext_vector_type(8))) short;

__device__ __forceinline__ unsigned short f2bf(float f) {
    union { float fp; unsigned int u; } v; v.fp = f;
    unsigned int u = v.u;
    return (unsigned short)((u + 0x7FFFu + ((u >> 16) & 1u)) >> 16);  // RNE
}

// ---------------- Router: logits (fp64 accum), softmax, top-2, renorm ----------------
__global__ void router_kernel(const float* __restrict__ x, const float* __restrict__ Wr,
                              int* __restrict__ ids, float* __restrict__ wts,
                              int* __restrict__ counts) {
    const int t = blockIdx.x;
    const int lane = threadIdx.x;  // 64
    const float* xr = x + (size_t)t * Dd;
    float xv[16];
#pragma unroll
    for (int i = 0; i < 16; ++i) xv[i] = xr[lane + 64 * i];
    double dot[Ee];
#pragma unroll
    for (int e = 0; e < Ee; ++e) {
        const float* wr = Wr + e * Dd;
        double s = 0.0;
#pragma unroll
        for (int i = 0; i < 16; ++i) s += (double)xv[i] * (double)wr[lane + 64 * i];
        dot[e] = s;
    }
#pragma unroll
    for (int off = 32; off >= 1; off >>= 1) {
#pragma unroll
        for (int e = 0; e < Ee; ++e) dot[e] += __shfl_xor(dot[e], off, 64);
    }
    if (lane == 0) {
        float lg[Ee];
#pragma unroll
        for (int e = 0; e < Ee; ++e) lg[e] = (float)dot[e];
        float m = lg[0];
        for (int e = 1; e < Ee; ++e) m = fmaxf(m, lg[e]);
        float ex[Ee]; float sum = 0.f;
        for (int e = 0; e < Ee; ++e) { ex[e] = expf(lg[e] - m); sum += ex[e]; }
        float s0 = -1.f, s1 = -1.f; int i0 = 0, i1 = 0;
        for (int e = 0; e < Ee; ++e) {
            float s = ex[e];
            if (s > s0)      { s1 = s0; i1 = i0; s0 = s; i0 = e; }
            else if (s > s1) { s1 = s; i1 = e; }
        }
        float inv = 1.f / sum;
        float sc0 = s0 * inv, sc1 = s1 * inv;
        float den = sc0 + sc1 + 1.1920929e-7f;  // float32 eps, matches reference
        ids[2 * t] = i0; ids[2 * t + 1] = i1;
        wts[2 * t] = sc0 / den; wts[2 * t + 1] = sc1 / den;
        atomicAdd(&counts[i0], 1);
        atomicAdd(&counts[i1], 1);
    }
}

// ---------------- x fp32 -> bf16 ----------------
__global__ void cvt_kernel(const float* __restrict__ x, unsigned short* __restrict__ xb) {
    int i = blockIdx.x * blockDim.x + threadIdx.x;  // one float4 per thread
    float4 v = ((const float4*)x)[i];
    ushort4 o;
    o.x = f2bf(v.x); o.y = f2bf(v.y); o.z = f2bf(v.z); o.w = f2bf(v.w);
    ((ushort4*)xb)[i] = o;
}

// ---------------- counts -> offsets + cursors ----------------
__global__ void scan_kernel(const int* __restrict__ counts, int* __restrict__ cursor,
                            int* __restrict__ eoff) {
    if (threadIdx.x == 0) {
        int acc = 0;
        for (int e = 0; e < Ee; ++e) { eoff[e] = acc; cursor[e] = acc; acc += counts[e]; }
        eoff[Ee] = acc;  // == Tt*Kk
    }
}

// ---------------- scatter tokens into per-expert buckets ----------------
__global__ void scatter_kernel(const int* __restrict__ ids, const float* __restrict__ wts,
                               int* __restrict__ cursor, int* __restrict__ rows,
                               float* __restrict__ roww) {
    int t = blockIdx.x * blockDim.x + threadIdx.x;
    if (t >= Tt) return;
#pragma unroll
    for (int k = 0; k < Kk; ++k) {
        int e = ids[2 * t + k];
        int pos = atomicAdd(&cursor[e], 1);
        rows[pos] = t;
        roww[pos] = wts[2 * t + k];
    }
}

// ---------------- GEMM1: H = relu(Xe@Wg^T) * (Xe@Wu^T), bf16 out ----------------
// tile 128(M) x 128(N) x 32(K); 8 waves (2x4); per wave 64x32 out per operand
__launch_bounds__(512, 2)
__global__ void gemm1_kernel(const unsigned short* __restrict__ xb,
                             const float* __restrict__ Wg, const float* __restrict__ Wu,
                             const int* __restrict__ eoff, const int* __restrict__ rows,
                             unsigned short* __restrict__ H) {
    const int e   = blockIdx.z;
    const int off = eoff[e];
    const int ne  = eoff[e + 1] - off;
    const int m0  = blockIdx.y * 128;
    if (m0 >= ne) return;
    const int n0  = blockIdx.x * 128;

    __shared__ __align__(16) unsigned short As[128][40];
    __shared__ __align__(16) unsigned short Bg[128][40];
    __shared__ __align__(16) unsigned short Bu[128][40];

    const int tid  = threadIdx.x;
    const int lane = tid & 63;
    const int wid  = tid >> 6;
    const int wm   = wid >> 2;       // 0..1
    const int wn   = wid & 3;        // 0..3
    const int lr   = lane & 15;
    const int lk   = (lane >> 4) * 8;

    const f32x4 zero = {0.f, 0.f, 0.f, 0.f};
    f32x4 accg[4][2], accu[4][2];
#pragma unroll
    for (int m = 0; m < 4; ++m)
#pragma unroll
        for (int n = 0; n < 2; ++n) { accg[m][n] = zero; accu[m][n] = zero; }

    // staging indices: A = 512 chunks of 8 bf16 (1/thread); B = 1024 float4 chunks/tile (2/thread)
    const int ar = tid >> 2, aj = tid & 3;
    const unsigned short* asrc = nullptr;
    if (m0 + ar < ne) asrc = xb + (size_t)rows[off + m0 + ar] * Dd + aj * 8;
    const size_t wbase = (size_t)e * Ff * Dd;
    const int f1 = tid >> 3, j1 = tid & 7;

    for (int kt = 0; kt < Dd; kt += 32) {
        __syncthreads();
        uint4 av = make_uint4(0, 0, 0, 0);
        if (asrc) av = *(const uint4*)(asrc + kt);
        *(uint4*)(&As[ar][aj * 8]) = av;
#pragma unroll
        for (int c = 0; c < 2; ++c) {
            const int f = f1 + c * 64;
            const size_t rowoff = wbase + (size_t)(n0 + f) * Dd + kt + j1 * 4;
            float4 g4 = *(const float4*)(Wg + rowoff);
            float4 u4 = *(const float4*)(Wu + rowoff);
            ushort4 gb, ub;
            gb.x = f2bf(g4.x); gb.y = f2bf(g4.y); gb.z = f2bf(g4.z); gb.w = f2bf(g4.w);
            ub.x = f2bf(u4.x); ub.y = f2bf(u4.y); ub.z = f2bf(u4.z); ub.w = f2bf(u4.w);
            *(ushort4*)(&Bg[f][j1 * 4]) = gb;
            *(ushort4*)(&Bu[f][j1 * 4]) = ub;
        }
        __syncthreads();

        bf16x8 af[4], bg[2], bu[2];
#pragma unroll
        for (int m = 0; m < 4; ++m)
            af[m] = *(const bf16x8*)(&As[wm * 64 + m * 16 + lr][lk]);
#pragma unroll
        for (int n = 0; n < 2; ++n) {
            bg[n] = *(const bf16x8*)(&Bg[wn * 32 + n * 16 + lr][lk]);
            bu[n] = *(const bf16x8*)(&Bu[wn * 32 + n * 16 + lr][lk]);
        }
#pragma unroll
        for (int m = 0; m < 4; ++m)
#pragma unroll
            for (int n = 0; n < 2; ++n) {
                accg[m][n] = __builtin_amdgcn_mfma_f32_16x16x32_bf16(af[m], bg[n], accg[m][n], 0, 0, 0);
                accu[m][n] = __builtin_amdgcn_mfma_f32_16x16x32_bf16(af[m], bu[n], accu[m][n], 0, 0, 0);
            }
    }

    // epilogue: h = relu(g)*u -> bf16 -> H[bucket_pos][f]
#pragma unroll
    for (int m = 0; m < 4; ++m) {
        const int rb = wm * 64 + m * 16 + (lane >> 4) * 4;
#pragma unroll
        for (int r = 0; r < 4; ++r) {
            const int i = m0 + rb + r;
            if (i < ne) {
                unsigned short* hp = H + (size_t)(off + i) * Ff + n0 + wn * 32;
#pragma unroll
                for (int n = 0; n < 2; ++n) {
                    const float g = accg[m][n][r];
                    const float h = fmaxf(g, 0.f) * accu[m][n][r];
                    hp[n * 16 + lr] = f2bf(h);
                }
            }
        }
    }
}

// ---------------- GEMM2: out[t] += w * (H @ Wd^T) ----------------
__launch_bounds__(512, 2)
__global__ void gemm2_kernel(const unsigned short* __restrict__ H,
                             const float* __restrict__ Wd,
                             const int* __restrict__ eoff, const int* __restrict__ rows,
                             const float* __restrict__ roww,
                             float* __restrict__ out) {
    const int e   = blockIdx.z;
    const int off = eoff[e];
    const int ne  = eoff[e + 1] - off;
    const int m0  = blockIdx.y * 128;
    if (m0 >= ne) return;
    const int n0  = blockIdx.x * 128;

    __shared__ __align__(16) unsigned short As[128][40];
    __shared__ __align__(16) unsigned short Bs[128][40];

    const int tid  = threadIdx.x;
    const int lane = tid & 63;
    const int wid  = tid >> 6;
    const int wm   = wid >> 2;
    const int wn   = wid & 3;
    const int lr   = lane & 15;
    const int lk   = (lane >> 4) * 8;

    const f32x4 zero = {0.f, 0.f, 0.f, 0.f};
    f32x4 acc[4][2];
#pragma unroll
    for (int m = 0; m < 4; ++m)
#pragma unroll
        for (int n = 0; n < 2; ++n) acc[m][n] = zero;

    const int ar = tid >> 2, aj = tid & 3;
    const unsigned short* asrc = nullptr;
    if (m0 + ar < ne) asrc = H + (size_t)(off + m0 + ar) * Ff + aj * 8;
    const size_t wdbase = (size_t)e * Dd * Ff;
    const int f1 = tid >> 3, j1 = tid & 7;

    for (int kt = 0; kt < Ff; kt += 32) {
        __syncthreads();
        uint4 av = make_uint4(0, 0, 0, 0);
        if (asrc) av = *(const uint4*)(asrc + kt);
        *(uint4*)(&As[ar][aj * 8]) = av;
#pragma unroll
        for (int c = 0; c < 2; ++c) {
            const int f = f1 + c * 64;
            float4 w4 = *(const float4*)(Wd + wdbase + (size_t)(n0 + f) * Ff + kt + j1 * 4);
            ushort4 wb;
            wb.x = f2bf(w4.x); wb.y = f2bf(w4.y); wb.z = f2bf(w4.z); wb.w = f2bf(w4.w);
            *(ushort4*)(&Bs[f][j1 * 4]) = wb;
        }
        __syncthreads();

        bf16x8 af[4], bfr[2];
#pragma unroll
        for (int m = 0; m < 4; ++m)
            af[m] = *(const bf16x8*)(&As[wm * 64 + m * 16 + lr][lk]);
#pragma unroll
        for (int n = 0; n < 2; ++n)
            bfr[n] = *(const bf16x8*)(&Bs[wn * 32 + n * 16 + lr][lk]);
#pragma unroll
        for (int m = 0; m < 4; ++m)
#pragma unroll
            for (int n = 0; n < 2; ++n)
                acc[m][n] = __builtin_amdgcn_mfma_f32_16x16x32_bf16(af[m], bfr[n], acc[m][n], 0, 0, 0);
    }

#pragma unroll
    for (int m = 0; m < 4; ++m) {
        const int rb = wm * 64 + m * 16 + (lane >> 4) * 4;
#pragma unroll
        for (int r = 0; r < 4; ++r) {
            const int i = m0 + rb + r;
            if (i < ne) {
                const int   t = rows[off + i];
                const float w = roww[off + i];
                float* op = out + (size_t)t * Dd + n0 + wn * 32;
#pragma unroll
                for (int n = 0; n < 2; ++n)
                    atomicAdd(&op[n * 16 + lr], w * acc[m][n][r]);
            }
        }
    }
}

extern "C" void kernel_launch(void* const* d_in, const int* in_sizes, int n_in,
                              void* d_out, int out_size, void* d_ws, size_t ws_size,
                              hipStream_t stream) {
    const float* x  = (const float*)d_in[0];
    const float* Wr = (const float*)d_in[1];
    const float* Wg = (const float*)d_in[2];
    const float* Wu = (const float*)d_in[3];
    const float* Wd = (const float*)d_in[4];
    float* out = (float*)d_out;
    char* ws = (char*)d_ws;

    const size_t OFF_IDS  = 256;
    const size_t OFF_WTS  = OFF_IDS  + (size_t)Tt * 2 * 4;
    const size_t OFF_ROWS = OFF_WTS  + (size_t)Tt * 2 * 4;
    const size_t OFF_ROWW = OFF_ROWS + (size_t)Tt * Kk * 4;
    const size_t OFF_XB   = OFF_ROWW + (size_t)Tt * Kk * 4;
    const size_t OFF_H    = OFF_XB   + (size_t)Tt * Dd * 2;
    const size_t NEED     = OFF_H    + (size_t)Tt * Kk * Ff * 2;
    if (ws_size < NEED) return;  // visible failure (out stays poisoned) rather than corruption

    int* counts = (int*)ws;
    int* cursor = (int*)(ws + 32);
    int* eoff   = (int*)(ws + 64);
    int* ids    = (int*)(ws + OFF_IDS);
    float* wts  = (float*)(ws + OFF_WTS);
    int* rows   = (int*)(ws + OFF_ROWS);
    float* roww = (float*)(ws + OFF_ROWW);
    unsigned short* xb = (unsigned short*)(ws + OFF_XB);
    unsigned short* H  = (unsigned short*)(ws + OFF_H);

    hipMemsetAsync(ws, 0, 256, stream);
    hipMemsetAsync(d_out, 0, (size_t)Tt * Dd * 4, stream);

    router_kernel <<<Tt, 64, 0, stream>>>(x, Wr, ids, wts, counts);
    cvt_kernel    <<<(Tt * Dd / 4) / 256, 256, 0, stream>>>(x, xb);
    scan_kernel   <<<1, 64, 0, stream>>>(counts, cursor, eoff);
    scatter_kernel<<<Tt / 256, 256, 0, stream>>>(ids, wts, cursor, rows, roww);
    gemm1_kernel  <<<dim3(Ff / 128, Tt / 128, Ee), 512, 0, stream>>>(xb, Wg, Wu, eoff, rows, H);
    gemm2_kernel  <<<dim3(Dd / 128, Tt / 128, Ee), 512, 0, stream>>>(H, Wd, eoff, rows, roww, out);
}

// Round 2
// 572.536 us; speedup vs baseline: 1.1263x; 1.1263x over previous
//
#include <hip/hip_runtime.h>
#include <hip/hip_bf16.h>

// Problem constants
#define Tt 4096   // B*L tokens
#define Dd 1024   // model dim
#define Ee 8      // experts
#define Kk 2      // top-k
#define Ff 4096   // DFF

using f32x4  = __attribute__((ext_vector_type(4))) float;
using bf16x8 = __attribute__((ext_vector_type(8))) short;

__device__ __forceinline__ unsigned short f2bf(float f) {
    union { float fp; unsigned int u; } v; v.fp = f;
    unsigned int u = v.u;
    return (unsigned short)((u + 0x7FFFu + ((u >> 16) & 1u)) >> 16);  // RNE
}

// async global->LDS, 16B per lane. dst must be wave-uniform base (lane*16 auto).
__device__ __forceinline__ void gl16(const void* g, void* l) {
    __builtin_amdgcn_global_load_lds(
        (const __attribute__((address_space(1))) void*)g,
        (__attribute__((address_space(3))) void*)l, 16, 0, 0);
}

// ---------------- Router: logits (fp64 accum), softmax, top-2, renorm ----------------
__global__ void router_kernel(const float* __restrict__ x, const float* __restrict__ Wr,
                              int* __restrict__ ids, float* __restrict__ wts,
                              int* __restrict__ counts) {
    const int t = blockIdx.x;
    const int lane = threadIdx.x;  // 64
    const float* xr = x + (size_t)t * Dd;
    float xv[16];
#pragma unroll
    for (int i = 0; i < 16; ++i) xv[i] = xr[lane + 64 * i];
    double dot[Ee];
#pragma unroll
    for (int e = 0; e < Ee; ++e) {
        const float* wr = Wr + e * Dd;
        double s = 0.0;
#pragma unroll
        for (int i = 0; i < 16; ++i) s += (double)xv[i] * (double)wr[lane + 64 * i];
        dot[e] = s;
    }
#pragma unroll
    for (int off = 32; off >= 1; off >>= 1) {
#pragma unroll
        for (int e = 0; e < Ee; ++e) dot[e] += __shfl_xor(dot[e], off, 64);
    }
    if (lane == 0) {
        float lg[Ee];
#pragma unroll
        for (int e = 0; e < Ee; ++e) lg[e] = (float)dot[e];
        float m = lg[0];
        for (int e = 1; e < Ee; ++e) m = fmaxf(m, lg[e]);
        float ex[Ee]; float sum = 0.f;
        for (int e = 0; e < Ee; ++e) { ex[e] = expf(lg[e] - m); sum += ex[e]; }
        float s0 = -1.f, s1 = -1.f; int i0 = 0, i1 = 0;
        for (int e = 0; e < Ee; ++e) {
            float s = ex[e];
            if (s > s0)      { s1 = s0; i1 = i0; s0 = s; i0 = e; }
            else if (s > s1) { s1 = s; i1 = e; }
        }
        float inv = 1.f / sum;
        float sc0 = s0 * inv, sc1 = s1 * inv;
        float den = sc0 + sc1 + 1.1920929e-7f;
        ids[2 * t] = i0; ids[2 * t + 1] = i1;
        wts[2 * t] = sc0 / den; wts[2 * t + 1] = sc1 / den;
        atomicAdd(&counts[i0], 1);
        atomicAdd(&counts[i1], 1);
    }
}

// ---------------- fp32 -> bf16 bulk convert (8 elems/thread) ----------------
__global__ void cvtw_kernel(const float* __restrict__ src, unsigned short* __restrict__ dst) {
    size_t i = ((size_t)blockIdx.x * blockDim.x + threadIdx.x) * 8;
    float4 a = *(const float4*)(src + i);
    float4 b = *(const float4*)(src + i + 4);
    uint4 o;
    o.x = (unsigned)f2bf(a.x) | ((unsigned)f2bf(a.y) << 16);
    o.y = (unsigned)f2bf(a.z) | ((unsigned)f2bf(a.w) << 16);
    o.z = (unsigned)f2bf(b.x) | ((unsigned)f2bf(b.y) << 16);
    o.w = (unsigned)f2bf(b.z) | ((unsigned)f2bf(b.w) << 16);
    *(uint4*)(dst + i) = o;
}

// ---------------- counts -> offsets + cursors ----------------
__global__ void scan_kernel(const int* __restrict__ counts, int* __restrict__ cursor,
                            int* __restrict__ eoff) {
    if (threadIdx.x == 0) {
        int acc = 0;
        for (int e = 0; e < Ee; ++e) { eoff[e] = acc; cursor[e] = acc; acc += counts[e]; }
        eoff[Ee] = acc;
    }
}

// ---------------- scatter tokens into per-expert buckets ----------------
__global__ void scatter_kernel(const int* __restrict__ ids, const float* __restrict__ wts,
                               int* __restrict__ cursor, int* __restrict__ rows,
                               float* __restrict__ roww) {
    int t = blockIdx.x * blockDim.x + threadIdx.x;
    if (t >= Tt) return;
#pragma unroll
    for (int k = 0; k < Kk; ++k) {
        int e = ids[2 * t + k];
        int pos = atomicAdd(&cursor[e], 1);
        rows[pos] = t;
        roww[pos] = wts[2 * t + k];
    }
}

// =================== bf16 GEMMs, m97 structure ===================
// tile 128x128, BK=32, 8 waves (2x4). LDS linear [128][32] per operand,
// XOR chunk swizzle: LDS(row, cc) holds global chunk (cc ^ ((row>>1)&3)).

__launch_bounds__(512, 4)
__global__ void gemm1_kernel(const unsigned short* __restrict__ xb,
                             const unsigned short* __restrict__ Wgb,
                             const unsigned short* __restrict__ Wub,
                             const int* __restrict__ eoff, const int* __restrict__ rows,
                             unsigned short* __restrict__ H) {
    const int e   = blockIdx.z;
    const int off = eoff[e];
    const int ne  = eoff[e + 1] - off;
    const int m0  = blockIdx.y * 128;
    if (m0 >= ne) return;
    const int n0  = blockIdx.x * 128;

    __shared__ __align__(16) unsigned short As[128 * 32];
    __shared__ __align__(16) unsigned short Bg[128 * 32];
    __shared__ __align__(16) unsigned short Bu[128 * 32];

    const int tid  = threadIdx.x;
    const int lane = tid & 63;
    const int wid  = tid >> 6;
    const int wm   = wid >> 2;       // 0..1
    const int wn   = wid & 3;        // 0..3
    const int lr   = lane & 15;
    const int lc   = lane >> 4;      // k-chunk 0..3

    // staging: chunk index == tid (byte = tid*16). row = tid>>2, lds chunk = tid&3.
    const int rowS = tid >> 2;
    const int ccS  = tid & 3;
    const int scS  = ccS ^ ((rowS >> 1) & 3);   // pre-swizzled source chunk
    int gr = m0 + rowS; if (gr > ne - 1) gr = ne - 1;
    const unsigned short* srcA = xb + (size_t)rows[off + gr] * Dd + scS * 8;
    const size_t wb = (size_t)e * Ff * Dd + (size_t)(n0 + rowS) * Dd + scS * 8;
    const unsigned short* srcG = Wgb + wb;
    const unsigned short* srcU = Wub + wb;
    unsigned short* dstA = As + wid * 512;   // 1024 B per wave
    unsigned short* dstG = Bg + wid * 512;
    unsigned short* dstU = Bu + wid * 512;

    const f32x4 zero = {0.f, 0.f, 0.f, 0.f};
    f32x4 accg[4][2], accu[4][2];
#pragma unroll
    for (int m = 0; m < 4; ++m)
#pragma unroll
        for (int n = 0; n < 2; ++n) { accg[m][n] = zero; accu[m][n] = zero; }

    // frag read offsets (ushort units): row*32 + (lc ^ ((row>>1)&3))*8
    int aoff[4], boff[2];
#pragma unroll
    for (int m = 0; m < 4; ++m) {
        int r = wm * 64 + m * 16 + lr;
        aoff[m] = r * 32 + ((lc ^ ((r >> 1) & 3)) << 3);
    }
#pragma unroll
    for (int n = 0; n < 2; ++n) {
        int r = wn * 32 + n * 16 + lr;
        boff[n] = r * 32 + ((lc ^ ((r >> 1) & 3)) << 3);
    }

    for (int kt = 0; kt < Dd; kt += 32) {
        __syncthreads();
        gl16(srcA + kt, dstA);
        gl16(srcG + kt, dstG);
        gl16(srcU + kt, dstU);
        __syncthreads();

        bf16x8 af[4], bg[2], bu[2];
#pragma unroll
        for (int m = 0; m < 4; ++m) af[m] = *(const bf16x8*)(As + aoff[m]);
#pragma unroll
        for (int n = 0; n < 2; ++n) {
            bg[n] = *(const bf16x8*)(Bg + boff[n]);
            bu[n] = *(const bf16x8*)(Bu + boff[n]);
        }
#pragma unroll
        for (int m = 0; m < 4; ++m)
#pragma unroll
            for (int n = 0; n < 2; ++n) {
                accg[m][n] = __builtin_amdgcn_mfma_f32_16x16x32_bf16(af[m], bg[n], accg[m][n], 0, 0, 0);
                accu[m][n] = __builtin_amdgcn_mfma_f32_16x16x32_bf16(af[m], bu[n], accu[m][n], 0, 0, 0);
            }
    }

#pragma unroll
    for (int m = 0; m < 4; ++m) {
        const int rb = wm * 64 + m * 16 + (lane >> 4) * 4;
#pragma unroll
        for (int r = 0; r < 4; ++r) {
            const int i = m0 + rb + r;
            if (i < ne) {
                unsigned short* hp = H + (size_t)(off + i) * Ff + n0 + wn * 32;
#pragma unroll
                for (int n = 0; n < 2; ++n) {
                    const float g = accg[m][n][r];
                    const float h = fmaxf(g, 0.f) * accu[m][n][r];
                    hp[n * 16 + lr] = f2bf(h);
                }
            }
        }
    }
}

__launch_bounds__(512, 4)
__global__ void gemm2_kernel(const unsigned short* __restrict__ H,
                             const unsigned short* __restrict__ Wdb,
                             const int* __restrict__ eoff, const int* __restrict__ rows,
                             const float* __restrict__ roww,
                             float* __restrict__ out) {
    const int e   = blockIdx.z;
    const int off = eoff[e];
    const int ne  = eoff[e + 1] - off;
    const int m0  = blockIdx.y * 128;
    if (m0 >= ne) return;
    const int n0  = blockIdx.x * 128;

    __shared__ __align__(16) unsigned short As[128 * 32];
    __shared__ __align__(16) unsigned short Bs[128 * 32];

    const int tid  = threadIdx.x;
    const int lane = tid & 63;
    const int wid  = tid >> 6;
    const int wm   = wid >> 2;
    const int wn   = wid & 3;
    const int lr   = lane & 15;
    const int lc   = lane >> 4;

    const int rowS = tid >> 2;
    const int ccS  = tid & 3;
    const int scS  = ccS ^ ((rowS >> 1) & 3);
    int gr = m0 + rowS; if (gr > ne - 1) gr = ne - 1;
    const unsigned short* srcA = H + (size_t)(off + gr) * Ff + scS * 8;
    const unsigned short* srcB = Wdb + (size_t)e * Dd * Ff + (size_t)(n0 + rowS) * Ff + scS * 8;
    unsigned short* dstA = As + wid * 512;
    unsigned short* dstB = Bs + wid * 512;

    const f32x4 zero = {0.f, 0.f, 0.f, 0.f};
    f32x4 acc[4][2];
#pragma unroll
    for (int m = 0; m < 4; ++m)
#pragma unroll
        for (int n = 0; n < 2; ++n) acc[m][n] = zero;

    int aoff[4], boff[2];
#pragma unroll
    for (int m = 0; m < 4; ++m) {
        int r = wm * 64 + m * 16 + lr;
        aoff[m] = r * 32 + ((lc ^ ((r >> 1) & 3)) << 3);
    }
#pragma unroll
    for (int n = 0; n < 2; ++n) {
        int r = wn * 32 + n * 16 + lr;
        boff[n] = r * 32 + ((lc ^ ((r >> 1) & 3)) << 3);
    }

    for (int kt = 0; kt < Ff; kt += 32) {
        __syncthreads();
        gl16(srcA + kt, dstA);
        gl16(srcB + kt, dstB);
        __syncthreads();

        bf16x8 af[4], bfr[2];
#pragma unroll
        for (int m = 0; m < 4; ++m) af[m] = *(const bf16x8*)(As + aoff[m]);
#pragma unroll
        for (int n = 0; n < 2; ++n) bfr[n] = *(const bf16x8*)(Bs + boff[n]);
#pragma unroll
        for (int m = 0; m < 4; ++m)
#pragma unroll
            for (int n = 0; n < 2; ++n)
                acc[m][n] = __builtin_amdgcn_mfma_f32_16x16x32_bf16(af[m], bfr[n], acc[m][n], 0, 0, 0);
    }

#pragma unroll
    for (int m = 0; m < 4; ++m) {
        const int rb = wm * 64 + m * 16 + (lane >> 4) * 4;
#pragma unroll
        for (int r = 0; r < 4; ++r) {
            const int i = m0 + rb + r;
            if (i < ne) {
                const int   t = rows[off + i];
                const float w = roww[off + i];
                float* op = out + (size_t)t * Dd + n0 + wn * 32;
#pragma unroll
                for (int n = 0; n < 2; ++n)
                    atomicAdd(&op[n * 16 + lr], w * acc[m][n][r]);
            }
        }
    }
}

// =================== fallback (round-1, fp32 weights inline-converted) ===================
__launch_bounds__(512, 2)
__global__ void gemm1_f32(const unsigned short* __restrict__ xb,
                          const float* __restrict__ Wg, const float* __restrict__ Wu,
                          const int* __restrict__ eoff, const int* __restrict__ rows,
                          unsigned short* __restrict__ H) {
    const int e   = blockIdx.z;
    const int off = eoff[e];
    const int ne  = eoff[e + 1] - off;
    const int m0  = blockIdx.y * 128;
    if (m0 >= ne) return;
    const int n0  = blockIdx.x * 128;

    __shared__ __align__(16) unsigned short As[128][40];
    __shared__ __align__(16) unsigned short Bg[128][40];
    __shared__ __align__(16) unsigned short Bu[128][40];

    const int tid  = threadIdx.x;
    const int lane = tid & 63;
    const int wid  = tid >> 6;
    const int wm   = wid >> 2;
    const int wn   = wid & 3;
    const int lr   = lane & 15;
    const int lk   = (lane >> 4) * 8;

    const f32x4 zero = {0.f, 0.f, 0.f, 0.f};
    f32x4 accg[4][2], accu[4][2];
#pragma unroll
    for (int m = 0; m < 4; ++m)
#pragma unroll
        for (int n = 0; n < 2; ++n) { accg[m][n] = zero; accu[m][n] = zero; }

    const int ar = tid >> 2, aj = tid & 3;
    const unsigned short* asrc = nullptr;
    if (m0 + ar < ne) asrc = xb + (size_t)rows[off + m0 + ar] * Dd + aj * 8;
    const size_t wbase = (size_t)e * Ff * Dd;
    const int f1 = tid >> 3, j1 = tid & 7;

    for (int kt = 0; kt < Dd; kt += 32) {
        __syncthreads();
        uint4 av = make_uint4(0, 0, 0, 0);
        if (asrc) av = *(const uint4*)(asrc + kt);
        *(uint4*)(&As[ar][aj * 8]) = av;
#pragma unroll
        for (int c = 0; c < 2; ++c) {
            const int f = f1 + c * 64;
            const size_t rowoff = wbase + (size_t)(n0 + f) * Dd + kt + j1 * 4;
            float4 g4 = *(const float4*)(Wg + rowoff);
            float4 u4 = *(const float4*)(Wu + rowoff);
            ushort4 gb, ub;
            gb.x = f2bf(g4.x); gb.y = f2bf(g4.y); gb.z = f2bf(g4.z); gb.w = f2bf(g4.w);
            ub.x = f2bf(u4.x); ub.y = f2bf(u4.y); ub.z = f2bf(u4.z); ub.w = f2bf(u4.w);
            *(ushort4*)(&Bg[f][j1 * 4]) = gb;
            *(ushort4*)(&Bu[f][j1 * 4]) = ub;
        }
        __syncthreads();

        bf16x8 af[4], bg[2], bu[2];
#pragma unroll
        for (int m = 0; m < 4; ++m)
            af[m] = *(const bf16x8*)(&As[wm * 64 + m * 16 + lr][lk]);
#pragma unroll
        for (int n = 0; n < 2; ++n) {
            bg[n] = *(const bf16x8*)(&Bg[wn * 32 + n * 16 + lr][lk]);
            bu[n] = *(const bf16x8*)(&Bu[wn * 32 + n * 16 + lr][lk]);
        }
#pragma unroll
        for (int m = 0; m < 4; ++m)
#pragma unroll
            for (int n = 0; n < 2; ++n) {
                accg[m][n] = __builtin_amdgcn_mfma_f32_16x16x32_bf16(af[m], bg[n], accg[m][n], 0, 0, 0);
                accu[m][n] = __builtin_amdgcn_mfma_f32_16x16x32_bf16(af[m], bu[n], accu[m][n], 0, 0, 0);
            }
    }

#pragma unroll
    for (int m = 0; m < 4; ++m) {
        const int rb = wm * 64 + m * 16 + (lane >> 4) * 4;
#pragma unroll
        for (int r = 0; r < 4; ++r) {
            const int i = m0 + rb + r;
            if (i < ne) {
                unsigned short* hp = H + (size_t)(off + i) * Ff + n0 + wn * 32;
#pragma unroll
                for (int n = 0; n < 2; ++n) {
                    const float g = accg[m][n][r];
                    const float h = fmaxf(g, 0.f) * accu[m][n][r];
                    hp[n * 16 + lr] = f2bf(h);
                }
            }
        }
    }
}

__launch_bounds__(512, 2)
__global__ void gemm2_f32(const unsigned short* __restrict__ H,
                          const float* __restrict__ Wd,
                          const int* __restrict__ eoff, const int* __restrict__ rows,
                          const float* __restrict__ roww,
                          float* __restrict__ out) {
    const int e   = blockIdx.z;
    const int off = eoff[e];
    const int ne  = eoff[e + 1] - off;
    const int m0  = blockIdx.y * 128;
    if (m0 >= ne) return;
    const int n0  = blockIdx.x * 128;

    __shared__ __align__(16) unsigned short As[128][40];
    __shared__ __align__(16) unsigned short Bs[128][40];

    const int tid  = threadIdx.x;
    const int lane = tid & 63;
    const int wid  = tid >> 6;
    const int wm   = wid >> 2;
    const int wn   = wid & 3;
    const int lr   = lane & 15;
    const int lk   = (lane >> 4) * 8;

    const f32x4 zero = {0.f, 0.f, 0.f, 0.f};
    f32x4 acc[4][2];
#pragma unroll
    for (int m = 0; m < 4; ++m)
#pragma unroll
        for (int n = 0; n < 2; ++n) acc[m][n] = zero;

    const int ar = tid >> 2, aj = tid & 3;
    const unsigned short* asrc = nullptr;
    if (m0 + ar < ne) asrc = H + (size_t)(off + m0 + ar) * Ff + aj * 8;
    const size_t wdbase = (size_t)e * Dd * Ff;
    const int f1 = tid >> 3, j1 = tid & 7;

    for (int kt = 0; kt < Ff; kt += 32) {
        __syncthreads();
        uint4 av = make_uint4(0, 0, 0, 0);
        if (asrc) av = *(const uint4*)(asrc + kt);
        *(uint4*)(&As[ar][aj * 8]) = av;
#pragma unroll
        for (int c = 0; c < 2; ++c) {
            const int f = f1 + c * 64;
            float4 w4 = *(const float4*)(Wd + wdbase + (size_t)(n0 + f) * Ff + kt + j1 * 4);
            ushort4 wb;
            wb.x = f2bf(w4.x); wb.y = f2bf(w4.y); wb.z = f2bf(w4.z); wb.w = f2bf(w4.w);
            *(ushort4*)(&Bs[f][j1 * 4]) = wb;
        }
        __syncthreads();

        bf16x8 af[4], bfr[2];
#pragma unroll
        for (int m = 0; m < 4; ++m)
            af[m] = *(const bf16x8*)(&As[wm * 64 + m * 16 + lr][lk]);
#pragma unroll
        for (int n = 0; n < 2; ++n)
            bfr[n] = *(const bf16x8*)(&Bs[wn * 32 + n * 16 + lr][lk]);
#pragma unroll
        for (int m = 0; m < 4; ++m)
#pragma unroll
            for (int n = 0; n < 2; ++n)
                acc[m][n] = __builtin_amdgcn_mfma_f32_16x16x32_bf16(af[m], bfr[n], acc[m][n], 0, 0, 0);
    }

#pragma unroll
    for (int m = 0; m < 4; ++m) {
        const int rb = wm * 64 + m * 16 + (lane >> 4) * 4;
#pragma unroll
        for (int r = 0; r < 4; ++r) {
            const int i = m0 + rb + r;
            if (i < ne) {
                const int   t = rows[off + i];
                const float w = roww[off + i];
                float* op = out + (size_t)t * Dd + n0 + wn * 32;
#pragma unroll
                for (int n = 0; n < 2; ++n)
                    atomicAdd(&op[n * 16 + lr], w * acc[m][n][r]);
            }
        }
    }
}

extern "C" void kernel_launch(void* const* d_in, const int* in_sizes, int n_in,
                              void* d_out, int out_size, void* d_ws, size_t ws_size,
                              hipStream_t stream) {
    const float* x  = (const float*)d_in[0];
    const float* Wr = (const float*)d_in[1];
    const float* Wg = (const float*)d_in[2];
    const float* Wu = (const float*)d_in[3];
    const float* Wd = (const float*)d_in[4];
    float* out = (float*)d_out;
    char* ws = (char*)d_ws;

    const size_t WELEM    = (size_t)Ee * Ff * Dd;            // 33.55M per weight tensor
    const size_t OFF_IDS  = 256;
    const size_t OFF_WTS  = OFF_IDS  + (size_t)Tt * 2 * 4;
    const size_t OFF_ROWS = OFF_WTS  + (size_t)Tt * 2 * 4;
    const size_t OFF_ROWW = OFF_ROWS + (size_t)Tt * Kk * 4;
    const size_t OFF_XB   = OFF_ROWW + (size_t)Tt * Kk * 4;
    const size_t OFF_H    = OFF_XB   + (size_t)Tt * Dd * 2;
    const size_t OFF_WG   = OFF_H    + (size_t)Tt * Kk * Ff * 2;
    const size_t OFF_WU   = OFF_WG   + WELEM * 2;
    const size_t OFF_WD   = OFF_WU   + WELEM * 2;
    const size_t NEED_FULL= OFF_WD   + WELEM * 2;   // ~277 MB
    const size_t NEED_OLD = OFF_WG;                  // ~76 MB
    if (ws_size < NEED_OLD) return;

    int* counts = (int*)ws;
    int* cursor = (int*)(ws + 32);
    int* eoff   = (int*)(ws + 64);
    int* ids    = (int*)(ws + OFF_IDS);
    float* wts  = (float*)(ws + OFF_WTS);
    int* rows   = (int*)(ws + OFF_ROWS);
    float* roww = (float*)(ws + OFF_ROWW);
    unsigned short* xb  = (unsigned short*)(ws + OFF_XB);
    unsigned short* H   = (unsigned short*)(ws + OFF_H);
    unsigned short* Wgb = (unsigned short*)(ws + OFF_WG);
    unsigned short* Wub = (unsigned short*)(ws + OFF_WU);
    unsigned short* Wdb = (unsigned short*)(ws + OFF_WD);

    hipMemsetAsync(ws, 0, 256, stream);
    hipMemsetAsync(d_out, 0, (size_t)Tt * Dd * 4, stream);

    router_kernel <<<Tt, 64, 0, stream>>>(x, Wr, ids, wts, counts);
    cvtw_kernel   <<<(Tt * Dd / 8) / 256, 256, 0, stream>>>(x, xb);
    scan_kernel   <<<1, 64, 0, stream>>>(counts, cursor, eoff);
    scatter_kernel<<<Tt / 256, 256, 0, stream>>>(ids, wts, cursor, rows, roww);

    if (ws_size >= NEED_FULL) {
        const int wblk = (int)(WELEM / 8 / 256);  // 16384
        cvtw_kernel<<<wblk, 256, 0, stream>>>(Wg, Wgb);
        cvtw_kernel<<<wblk, 256, 0, stream>>>(Wu, Wub);
        cvtw_kernel<<<wblk, 256, 0, stream>>>(Wd, Wdb);
        gemm1_kernel<<<dim3(Ff / 128, Tt / 128, Ee), 512, 0, stream>>>(xb, Wgb, Wub, eoff, rows, H);
        gemm2_kernel<<<dim3(Dd / 128, Tt / 128, Ee), 512, 0, stream>>>(H, Wdb, eoff, rows, roww, out);
    } else {
        gemm1_f32<<<dim3(Ff / 128, Tt / 128, Ee), 512, 0, stream>>>(xb, Wg, Wu, eoff, rows, H);
        gemm2_f32<<<dim3(Dd / 128, Tt / 128, Ee), 512, 0, stream>>>(H, Wd, eoff, rows, roww, out);
    }
}

// Round 4
// 515.041 us; speedup vs baseline: 1.2520x; 1.1116x over previous
//
#include <hip/hip_runtime.h>
#include <hip/hip_bf16.h>

// Problem constants
#define Tt 4096   // B*L tokens
#define Dd 1024   // model dim
#define Ee 8      // experts
#define Kk 2      // top-k
#define Ff 4096   // DFF

using f32x4  = __attribute__((ext_vector_type(4))) float;
using bf16x8 = __attribute__((ext_vector_type(8))) short;

__device__ __forceinline__ unsigned short f2bf(float f) {
    union { float fp; unsigned int u; } v; v.fp = f;
    unsigned int u = v.u;
    return (unsigned short)((u + 0x7FFFu + ((u >> 16) & 1u)) >> 16);  // RNE
}

// async global->LDS, 16B per lane. dst must be wave-uniform base (lane*16 auto).
__device__ __forceinline__ void gl16(const void* g, void* l) {
    __builtin_amdgcn_global_load_lds(
        (const __attribute__((address_space(1))) void*)g,
        (__attribute__((address_space(3))) void*)l, 16, 0, 0);
}

// ---------------- Router: logits (fp64 accum), softmax, top-2, renorm ----------------
__global__ void router_kernel(const float* __restrict__ x, const float* __restrict__ Wr,
                              int* __restrict__ ids, float* __restrict__ wts,
                              int* __restrict__ counts) {
    const int t = blockIdx.x;
    const int lane = threadIdx.x;  // 64
    const float* xr = x + (size_t)t * Dd;
    float xv[16];
#pragma unroll
    for (int i = 0; i < 16; ++i) xv[i] = xr[lane + 64 * i];
    double dot[Ee];
#pragma unroll
    for (int e = 0; e < Ee; ++e) {
        const float* wr = Wr + e * Dd;
        double s = 0.0;
#pragma unroll
        for (int i = 0; i < 16; ++i) s += (double)xv[i] * (double)wr[lane + 64 * i];
        dot[e] = s;
    }
#pragma unroll
    for (int off = 32; off >= 1; off >>= 1) {
#pragma unroll
        for (int e = 0; e < Ee; ++e) dot[e] += __shfl_xor(dot[e], off, 64);
    }
    if (lane == 0) {
        float lg[Ee];
#pragma unroll
        for (int e = 0; e < Ee; ++e) lg[e] = (float)dot[e];
        float m = lg[0];
        for (int e = 1; e < Ee; ++e) m = fmaxf(m, lg[e]);
        float ex[Ee]; float sum = 0.f;
        for (int e = 0; e < Ee; ++e) { ex[e] = expf(lg[e] - m); sum += ex[e]; }
        float s0 = -1.f, s1 = -1.f; int i0 = 0, i1 = 0;
        for (int e = 0; e < Ee; ++e) {
            float s = ex[e];
            if (s > s0)      { s1 = s0; i1 = i0; s0 = s; i0 = e; }
            else if (s > s1) { s1 = s; i1 = e; }
        }
        float inv = 1.f / sum;
        float sc0 = s0 * inv, sc1 = s1 * inv;
        float den = sc0 + sc1 + 1.1920929e-7f;
        ids[2 * t] = i0; ids[2 * t + 1] = i1;
        wts[2 * t] = sc0 / den; wts[2 * t + 1] = sc1 / den;
        atomicAdd(&counts[i0], 1);
        atomicAdd(&counts[i1], 1);
    }
}

// ---------------- fp32 -> bf16 bulk convert (8 elems/thread) ----------------
__global__ void cvtw_kernel(const float* __restrict__ src, unsigned short* __restrict__ dst) {
    size_t i = ((size_t)blockIdx.x * blockDim.x + threadIdx.x) * 8;
    float4 a = *(const float4*)(src + i);
    float4 b = *(const float4*)(src + i + 4);
    uint4 o;
    o.x = (unsigned)f2bf(a.x) | ((unsigned)f2bf(a.y) << 16);
    o.y = (unsigned)f2bf(a.z) | ((unsigned)f2bf(a.w) << 16);
    o.z = (unsigned)f2bf(b.x) | ((unsigned)f2bf(b.y) << 16);
    o.w = (unsigned)f2bf(b.z) | ((unsigned)f2bf(b.w) << 16);
    *(uint4*)(dst + i) = o;
}

// ---------------- Wg/Wu -> interleaved bf16 Wgu ----------------
// Wgu row j (0..8191) per expert: fg=j>>5, s=(j>>4)&1, fi=j&15 -> f=fg*16+fi,
// source = (s ? Wu : Wg)[e][f][:]. 16-row groups alternate g/u for same f-range.
__global__ void cvt_wgu_kernel(const float* __restrict__ Wg, const float* __restrict__ Wu,
                               unsigned short* __restrict__ Wgu) {
    size_t tid = (size_t)blockIdx.x * blockDim.x + threadIdx.x;
    size_t row = tid >> 7;          // 128 threads per 1024-elem row
    int dc  = (int)(tid & 127);
    int e   = (int)(row >> 13);     // 8192 rows/expert
    int j   = (int)(row & 8191);
    int fg = j >> 5, s = (j >> 4) & 1, fi = j & 15;
    int f  = fg * 16 + fi;
    const float* src = (s ? Wu : Wg) + ((size_t)e * Ff + f) * Dd + dc * 8;
    float4 a = *(const float4*)(src);
    float4 b = *(const float4*)(src + 4);
    uint4 o;
    o.x = (unsigned)f2bf(a.x) | ((unsigned)f2bf(a.y) << 16);
    o.y = (unsigned)f2bf(a.z) | ((unsigned)f2bf(a.w) << 16);
    o.z = (unsigned)f2bf(b.x) | ((unsigned)f2bf(b.y) << 16);
    o.w = (unsigned)f2bf(b.z) | ((unsigned)f2bf(b.w) << 16);
    *(uint4*)(Wgu + row * Dd + dc * 8) = o;
}

// ---------------- counts -> offsets + cursors ----------------
__global__ void scan_kernel(const int* __restrict__ counts, int* __restrict__ cursor,
                            int* __restrict__ eoff) {
    if (threadIdx.x == 0) {
        int acc = 0;
        for (int e = 0; e < Ee; ++e) { eoff[e] = acc; cursor[e] = acc; acc += counts[e]; }
        eoff[Ee] = acc;
    }
}

// ---------------- scatter tokens into per-expert buckets ----------------
__global__ void scatter_kernel(const int* __restrict__ ids, const float* __restrict__ wts,
                               int* __restrict__ cursor, int* __restrict__ rows,
                               float* __restrict__ roww) {
    int t = blockIdx.x * blockDim.x + threadIdx.x;
    if (t >= Tt) return;
#pragma unroll
    for (int k = 0; k < Kk; ++k) {
        int e = ids[2 * t + k];
        int pos = atomicAdd(&cursor[e], 1);
        rows[pos] = t;
        roww[pos] = wts[2 * t + k];
    }
}

// =================== unified 256x256 BK=64 8-wave 4-phase counted-vmcnt GEMM ===================
// G2=false (gemm1): A = xb rows via rows[], B = Wgu (N=8192), K=1024, epilogue relu(g)*u -> H.
// G2=true  (gemm2): A = H rows (direct),   B = Wdb (N=1024), K=4096, epilogue w*acc atomicAdd out.
// Tail fix: vmcnt(4) only while t+2<NT (newest-4 = A(t+2)); else vmcnt(0) — the newest-4 would
// otherwise be the B(t+1) loads the NEXT tile reads (the round-3 race).

#define MFMA_BF16(a, b, c) __builtin_amdgcn_mfma_f32_16x16x32_bf16(a, b, c, 0, 0, 0)

template<bool G2>
__launch_bounds__(512, 1)
__global__ void gemm_8ph(const unsigned short* __restrict__ Abase,
                         const unsigned short* __restrict__ Bbase,
                         const int* __restrict__ eoff, const int* __restrict__ rows,
                         const float* __restrict__ roww,
                         unsigned short* __restrict__ H,
                         float* __restrict__ out) {
    constexpr int KLEN = G2 ? Ff : Dd;       // A/B row length
    constexpr int NT   = KLEN / 64;          // K-tiles
    const int e   = blockIdx.z;
    const int off = eoff[e];
    const int ne  = eoff[e + 1] - off;
    const int m0  = blockIdx.y * 256;
    if (m0 >= ne) return;
    const int n0  = blockIdx.x * 256;

    __shared__ __align__(16) unsigned short L[65536];  // 128 KiB
    unsigned short* Ls = L;

    const int tid  = threadIdx.x;
    const int lane = tid & 63;
    const int w    = tid >> 6;        // wave 0..7
    const int wr   = w >> 2;          // 0..1 (M half)
    const int wc   = w & 3;           // 0..3 (N quarter)
    const int lr   = lane & 15;
    const int lc   = lane >> 4;       // 0..3

    // --- staging addressing ---
    const int sr = lane >> 3;                 // 0..7
    const int cA = (lane & 7) ^ sr;           // pre-swizzled source chunk
    int asrc[4];
#pragma unroll
    for (int qq = 0; qq < 4; ++qq) {
        int rr = m0 + qq * 64 + w * 8 + sr;
        if (rr > ne - 1) rr = ne - 1;
        asrc[qq] = (G2 ? (off + rr) : rows[off + rr]) * KLEN + cA * 8;
    }
    const unsigned short* Bp = Bbase + (size_t)e * (G2 ? (size_t)Dd * Ff : (size_t)8192 * Dd);
    int bsrc[4];
#pragma unroll
    for (int qq = 0; qq < 4; ++qq) {
        int rN = n0 + qq * 64 + w * 8 + sr;
        bsrc[qq] = rN * KLEN + cA * 8;
    }

#define STAGE_A(T, Hh) { const int bo_ = ((T) & 1) * 32768; const int kt_ = (T) * 64;            \
    gl16(Abase + asrc[2*(Hh)]   + kt_, Ls + bo_ + (2*(Hh))   * 4096 + w * 512);                  \
    gl16(Abase + asrc[2*(Hh)+1] + kt_, Ls + bo_ + (2*(Hh)+1) * 4096 + w * 512); }
#define STAGE_B(T, Hh) { const int bo_ = ((T) & 1) * 32768 + 16384; const int kt_ = (T) * 64;    \
    gl16(Bp + bsrc[2*(Hh)]   + kt_, Ls + bo_ + (2*(Hh))   * 4096 + w * 512);                     \
    gl16(Bp + bsrc[2*(Hh)+1] + kt_, Ls + bo_ + (2*(Hh)+1) * 4096 + w * 512); }

    // --- fragment read offsets (ushort units) ---
    const int ccx0 = ((0 * 4 + lc) ^ (lr & 7)) * 8;
    const int ccx1 = ((1 * 4 + lc) ^ (lr & 7)) * 8;
    const int aB = wr * 8192 + lr * 64;
    const int bB = 16384 + (wc >> 1) * 8192 + (wc & 1) * 4096 + lr * 64;

    f32x4 acc[8][4];
#pragma unroll
    for (int m = 0; m < 8; ++m)
#pragma unroll
        for (int n = 0; n < 4; ++n) acc[m][n] = (f32x4){0.f, 0.f, 0.f, 0.f};

    // --- prologue: tile0 all 4 halves + tile1 A halves; wait leaves A(1) (4) in flight ---
    STAGE_A(0, 0); STAGE_A(0, 1); STAGE_B(0, 0); STAGE_B(0, 1);
    STAGE_A(1, 0); STAGE_A(1, 1);
    asm volatile("s_waitcnt vmcnt(4)" ::: "memory");
    __builtin_amdgcn_sched_barrier(0);
    __builtin_amdgcn_s_barrier();

    bf16x8 a0[8], a1[8], b0[4], b1[4];

    for (int t = 0; t < NT; ++t) {
        const int bo = (t & 1) * 32768;
        // ---- P1: read a_kk0 + b_kk0; stage (t+1).B0 ----
#pragma unroll
        for (int m = 0; m < 8; ++m) a0[m] = *(const bf16x8*)(Ls + bo + aB + m * 1024 + ccx0);
#pragma unroll
        for (int n = 0; n < 4; ++n) b0[n] = *(const bf16x8*)(Ls + bo + bB + n * 1024 + ccx0);
        if (t + 1 < NT) STAGE_B(t + 1, 0);
        __builtin_amdgcn_s_barrier();
        asm volatile("s_waitcnt lgkmcnt(0)" ::: "memory");
        __builtin_amdgcn_sched_barrier(0);
        __builtin_amdgcn_s_setprio(1);
#pragma unroll
        for (int m = 0; m < 8; ++m) {
            acc[m][0] = MFMA_BF16(a0[m], b0[0], acc[m][0]);
            acc[m][1] = MFMA_BF16(a0[m], b0[1], acc[m][1]);
        }
        __builtin_amdgcn_s_setprio(0);
        __builtin_amdgcn_s_barrier();
        // ---- P2: read a_kk1; stage (t+1).B1; MFMA kk0 nh1; lgkm-drain ----
#pragma unroll
        for (int m = 0; m < 8; ++m) a1[m] = *(const bf16x8*)(Ls + bo + aB + m * 1024 + ccx1);
        if (t + 1 < NT) STAGE_B(t + 1, 1);
        __builtin_amdgcn_s_barrier();
        __builtin_amdgcn_s_setprio(1);
#pragma unroll
        for (int m = 0; m < 8; ++m) {
            acc[m][2] = MFMA_BF16(a0[m], b0[2], acc[m][2]);
            acc[m][3] = MFMA_BF16(a0[m], b0[3], acc[m][3]);
        }
        __builtin_amdgcn_s_setprio(0);
        asm volatile("s_waitcnt lgkmcnt(0)" ::: "memory");
        __builtin_amdgcn_sched_barrier(0);
        __builtin_amdgcn_s_barrier();
        // ---- P3: read b_kk1; stage (t+2).A0; MFMA kk1 nh0 ----
#pragma unroll
        for (int n = 0; n < 4; ++n) b1[n] = *(const bf16x8*)(Ls + bo + bB + n * 1024 + ccx1);
        if (t + 2 < NT) STAGE_A(t + 2, 0);
        __builtin_amdgcn_s_barrier();
        asm volatile("s_waitcnt lgkmcnt(0)" ::: "memory");
        __builtin_amdgcn_sched_barrier(0);
        __builtin_amdgcn_s_setprio(1);
#pragma unroll
        for (int m = 0; m < 8; ++m) {
            acc[m][0] = MFMA_BF16(a1[m], b1[0], acc[m][0]);
            acc[m][1] = MFMA_BF16(a1[m], b1[1], acc[m][1]);
        }
        __builtin_amdgcn_s_setprio(0);
        __builtin_amdgcn_s_barrier();
        // ---- P4: stage (t+2).A1; MFMA kk1 nh1; counted vmcnt (tail-corrected) ----
        if (t + 2 < NT) STAGE_A(t + 2, 1);
        __builtin_amdgcn_s_setprio(1);
#pragma unroll
        for (int m = 0; m < 8; ++m) {
            acc[m][2] = MFMA_BF16(a1[m], b1[2], acc[m][2]);
            acc[m][3] = MFMA_BF16(a1[m], b1[3], acc[m][3]);
        }
        __builtin_amdgcn_s_setprio(0);
        if (t + 2 < NT) { asm volatile("s_waitcnt vmcnt(4)" ::: "memory"); }
        else            { asm volatile("s_waitcnt vmcnt(0)" ::: "memory"); }
        __builtin_amdgcn_sched_barrier(0);
        __builtin_amdgcn_s_barrier();
    }

    if constexpr (!G2) {
        // ---- epilogue gemm1: h = relu(g)*u in-register, write H ----
        const int fg16 = ((n0 + wc * 64) >> 5) * 16 + lr;
#pragma unroll
        for (int m = 0; m < 8; ++m) {
            const int itok = m0 + wr * 128 + m * 16 + (lane >> 4) * 4;
#pragma unroll
            for (int r = 0; r < 4; ++r) {
                const int i = itok + r;
                if (i < ne) {
                    unsigned short* hp = H + (size_t)(off + i) * Ff;
#pragma unroll
                    for (int np = 0; np < 2; ++np) {
                        const float g = acc[m][2 * np][r];
                        const float u = acc[m][2 * np + 1][r];
                        hp[fg16 + np * 16] = f2bf(fmaxf(g, 0.f) * u);
                    }
                }
            }
        }
    } else {
        // ---- epilogue gemm2: out[t][d] += w * acc ----
        const int dbase = n0 + wc * 64;
#pragma unroll
        for (int m = 0; m < 8; ++m) {
            const int ib = m0 + wr * 128 + m * 16 + (lane >> 4) * 4;
#pragma unroll
            for (int r = 0; r < 4; ++r) {
                const int i = ib + r;
                if (i < ne) {
                    const int   t  = rows[off + i];
                    const float wg = roww[off + i];
                    float* op = out + (size_t)t * Dd + dbase + lr;
#pragma unroll
                    for (int n = 0; n < 4; ++n)
                        atomicAdd(&op[n * 16], wg * acc[m][n][r]);
                }
            }
        }
    }
#undef STAGE_A
#undef STAGE_B
}

extern "C" void kernel_launch(void* const* d_in, const int* in_sizes, int n_in,
                              void* d_out, int out_size, void* d_ws, size_t ws_size,
                              hipStream_t stream) {
    const float* x  = (const float*)d_in[0];
    const float* Wr = (const float*)d_in[1];
    const float* Wg = (const float*)d_in[2];
    const float* Wu = (const float*)d_in[3];
    const float* Wd = (const float*)d_in[4];
    float* out = (float*)d_out;
    char* ws = (char*)d_ws;

    const size_t WELEM    = (size_t)Ee * Ff * Dd;            // 33.55M
    const size_t OFF_IDS  = 256;
    const size_t OFF_WTS  = OFF_IDS  + (size_t)Tt * 2 * 4;
    const size_t OFF_ROWS = OFF_WTS  + (size_t)Tt * 2 * 4;
    const size_t OFF_ROWW = OFF_ROWS + (size_t)Tt * Kk * 4;
    const size_t OFF_XB   = OFF_ROWW + (size_t)Tt * Kk * 4;
    const size_t OFF_H    = OFF_XB   + (size_t)Tt * Dd * 2;
    const size_t OFF_WGU  = OFF_H    + (size_t)Tt * Kk * Ff * 2;
    const size_t OFF_WD   = OFF_WGU  + WELEM * 2 * 2;        // Wgu = 2*WELEM bf16
    const size_t NEED     = OFF_WD   + WELEM * 2;            // ~277 MB
    if (ws_size < NEED) return;

    int* counts = (int*)ws;
    int* cursor = (int*)(ws + 32);
    int* eoff   = (int*)(ws + 64);
    int* ids    = (int*)(ws + OFF_IDS);
    float* wts  = (float*)(ws + OFF_WTS);
    int* rows   = (int*)(ws + OFF_ROWS);
    float* roww = (float*)(ws + OFF_ROWW);
    unsigned short* xb  = (unsigned short*)(ws + OFF_XB);
    unsigned short* H   = (unsigned short*)(ws + OFF_H);
    unsigned short* Wgu = (unsigned short*)(ws + OFF_WGU);
    unsigned short* Wdb = (unsigned short*)(ws + OFF_WD);

    hipMemsetAsync(ws, 0, 256, stream);
    hipMemsetAsync(d_out, 0, (size_t)Tt * Dd * 4, stream);

    router_kernel  <<<Tt, 64, 0, stream>>>(x, Wr, ids, wts, counts);
    cvtw_kernel    <<<(Tt * Dd / 8) / 256, 256, 0, stream>>>(x, xb);
    scan_kernel    <<<1, 64, 0, stream>>>(counts, cursor, eoff);
    scatter_kernel <<<Tt / 256, 256, 0, stream>>>(ids, wts, cursor, rows, roww);

    cvt_wgu_kernel <<<(int)(WELEM * 2 / 8 / 256), 256, 0, stream>>>(Wg, Wu, Wgu);
    cvtw_kernel    <<<(int)(WELEM / 8 / 256), 256, 0, stream>>>(Wd, Wdb);

    gemm_8ph<false><<<dim3(2 * Ff / 256, Tt / 256, Ee), 512, 0, stream>>>(
        xb, Wgu, eoff, rows, roww, H, out);
    gemm_8ph<true> <<<dim3(Dd / 256, Tt / 256, Ee), 512, 0, stream>>>(
        H, Wdb, eoff, rows, roww, H, out);
}